// Round 5
// baseline (43.472 us; speedup 1.0000x reference)
//
#include <hip/hip_runtime.h>

// QRNN fused kernel for MI355X.
// B=64, S=2048, VOCAB=128, HIDDEN=256, gates=768, emb=124, num=7.
//
//  - precompute_kernel (one grid, three roles):
//      blocks 0..63   : GEMM G[768][128e] = Wc[:,:124] @ emb^T (emb^T in LDS, pad 129),
//                       b_num folded via bias. Writes interleaved exp2-domain table
//                       G4[e][p] = {z'(2p), f'(2p), z'(2p+1), f'(2p+1)} and Go[e][j].
//      block  64      : Wg4/Wgo2 numeric-path weights (Wc[:,124:]@W_num, scaled) +
//                       zero pad record Xp[B*S].
//      blocks 65..192 : packed per-step records Xp[b*S+t] = {eo=e<<11, x0..x6} (32B)
//                       -> scan does ONE uniform s_load batch per step.
//  - scan_kernel: affine recurrence h = f*h + (1-f)*z, chunked scan (32 x 64 steps).
//      128 threads/block, 2 hidden channels per thread. Per step: one s_load record,
//      one global_load_dwordx4 (G4 row), 14 v_pk_fma_f32, 4 exp2 + 2 shared rcp,
//      6 scan VALU. Explicit next-step register prefetch (record + G4 row).
//  - combine_kernel: fold 32 chunk affines, apply o (last step), dot W_out.

typedef float f32x2 __attribute__((ext_vector_type(2)));
typedef float f32x4 __attribute__((ext_vector_type(4)));

#define NB 64
#define NS 2048
#define NH 256
#define CHUNKS 32
#define STEPS (NS / CHUNKS)   // 64
#define LOG2E 1.4426950408889634f
#define PAD 129

static __device__ __forceinline__ f32x4 splat4(float v) { return (f32x4){v, v, v, v}; }

__global__ __launch_bounds__(256) void precompute_kernel(
    const float* __restrict__ X,     // [B][S][8]
    const float* __restrict__ emb,   // [128][124]
    const float* __restrict__ Wn,    // [4][7]
    const float* __restrict__ bn,    // [4]
    const float* __restrict__ Wc,    // [768][128]
    const float* __restrict__ bc,    // [768]
    f32x4* __restrict__ G4,          // out [128e][128p]
    float* __restrict__ Go,          // out [128e][256j]
    f32x4* __restrict__ Wg4,         // out [7][128]
    f32x2* __restrict__ Wgo2,        // out [7][128]
    float* __restrict__ Xp)          // out [B*S+1][8] packed records
{
    __shared__ float M[124 * PAD];   // emb^T staged: M[k*PAD + e] = emb[e][k]
    const int tid = threadIdx.x;
    const int blk = blockIdx.x;

    if (blk < 64) {
        {
            const int e = tid >> 1, half = tid & 1;
            const f32x4* er4 = (const f32x4*)(emb + (size_t)e * 124);
            #pragma unroll
            for (int i = 0; i < 16; ++i) {
                const int idx = half * 16 + i;
                if (idx < 31) {
                    const f32x4 v = er4[idx];
                    const int k0 = idx * 4;
                    M[(k0 + 0) * PAD + e] = v.x;
                    M[(k0 + 1) * PAD + e] = v.y;
                    M[(k0 + 2) * PAD + e] = v.z;
                    M[(k0 + 3) * PAD + e] = v.w;
                }
            }
        }
        __syncthreads();

        const int e = tid & 127;
        const int s = tid >> 7;           // 0 or 1
        const int j0 = blk * 4 + s * 2;   // channels j0, j0+1
        const int p  = blk * 2 + s;       // pair index

        float bnv[4];
        #pragma unroll
        for (int m = 0; m < 4; ++m) bnv[m] = bn[m];

        float acc[2][3] = {{0.f,0.f,0.f},{0.f,0.f,0.f}};
        const f32x4* wz4[2]; const f32x4* wf4[2]; const f32x4* wo4[2];
        #pragma unroll
        for (int i = 0; i < 2; ++i) {
            wz4[i] = (const f32x4*)(Wc + (size_t)(j0 + i) * 128);
            wf4[i] = (const f32x4*)(Wc + (size_t)(j0 + i + 256) * 128);
            wo4[i] = (const f32x4*)(Wc + (size_t)(j0 + i + 512) * 128);
        }

        for (int kb = 0; kb < 31; ++kb) {
            f32x4 w[2][3];
            #pragma unroll
            for (int i = 0; i < 2; ++i) {
                w[i][0] = wz4[i][kb];
                w[i][1] = wf4[i][kb];
                w[i][2] = wo4[i][kb];
            }
            #pragma unroll
            for (int u = 0; u < 4; ++u) {
                const float mv = M[(kb * 4 + u) * PAD + e];
                #pragma unroll
                for (int i = 0; i < 2; ++i) {
                    acc[i][0] = fmaf(w[i][0][u], mv, acc[i][0]);
                    acc[i][1] = fmaf(w[i][1][u], mv, acc[i][1]);
                    acc[i][2] = fmaf(w[i][2][u], mv, acc[i][2]);
                }
            }
        }

        float azv[2], afv[2], aov[2];
        #pragma unroll
        for (int i = 0; i < 2; ++i) {
            const int j = j0 + i;
            float az = acc[i][0] + bc[j];
            float af = acc[i][1] + bc[j + 256];
            float ao = acc[i][2] + bc[j + 512];
            const f32x4 tz = wz4[i][31];
            const f32x4 tf = wf4[i][31];
            const f32x4 to = wo4[i][31];
            #pragma unroll
            for (int m = 0; m < 4; ++m) {
                az = fmaf(tz[m], bnv[m], az);
                af = fmaf(tf[m], bnv[m], af);
                ao = fmaf(to[m], bnv[m], ao);
            }
            azv[i] = az; afv[i] = af; aov[i] = ao;
        }
        G4[(size_t)e * 128 + p] = (f32x4){azv[0] * (-2.0f * LOG2E), afv[0] * (-LOG2E),
                                          azv[1] * (-2.0f * LOG2E), afv[1] * (-LOG2E)};
        Go[(size_t)e * NH + j0]     = aov[0] * (-LOG2E);
        Go[(size_t)e * NH + j0 + 1] = aov[1] * (-LOG2E);
    } else if (blk == 64) {
        if (tid < 128) {
            #pragma unroll
            for (int n = 0; n < 7; ++n) {
                float s0[3] = {0.f,0.f,0.f}, s1[3] = {0.f,0.f,0.f};
                #pragma unroll
                for (int m = 0; m < 4; ++m) {
                    const float wnm = Wn[m * 7 + n];
                    const int j0 = 2 * tid, j1 = 2 * tid + 1;
                    s0[0] = fmaf(Wc[(size_t)j0 * 128 + 124 + m], wnm, s0[0]);
                    s0[1] = fmaf(Wc[(size_t)(j0 + 256) * 128 + 124 + m], wnm, s0[1]);
                    s0[2] = fmaf(Wc[(size_t)(j0 + 512) * 128 + 124 + m], wnm, s0[2]);
                    s1[0] = fmaf(Wc[(size_t)j1 * 128 + 124 + m], wnm, s1[0]);
                    s1[1] = fmaf(Wc[(size_t)(j1 + 256) * 128 + 124 + m], wnm, s1[1]);
                    s1[2] = fmaf(Wc[(size_t)(j1 + 512) * 128 + 124 + m], wnm, s1[2]);
                }
                Wg4[n * 128 + tid]  = (f32x4){s0[0] * (-2.0f * LOG2E), s0[1] * (-LOG2E),
                                              s1[0] * (-2.0f * LOG2E), s1[1] * (-LOG2E)};
                Wgo2[n * 128 + tid] = (f32x2){s0[2] * (-LOG2E), s1[2] * (-LOG2E)};
            }
        } else if (tid < 136) {
            Xp[(size_t)NB * NS * 8 + (tid - 128)] = 0.0f;   // pad record (eo=0)
        }
    } else {
        // packed record extraction: 128 blocks x 1024 records
        const f32x4* X4 = (const f32x4*)X;
        f32x4* Xp4 = (f32x4*)Xp;
        const int base = (blk - 65) * 1024 + tid;
        #pragma unroll
        for (int u = 0; u < 4; ++u) {
            const int idx = base + u * 256;
            f32x4 xa = X4[(size_t)idx * 2];
            const f32x4 xb = X4[(size_t)idx * 2 + 1];
            xa.x = __int_as_float(((int)xa.x) << 11);   // byte offset of G4 row
            Xp4[(size_t)idx * 2]     = xa;
            Xp4[(size_t)idx * 2 + 1] = xb;
        }
    }
}

__global__ __launch_bounds__(128) void scan_kernel(
    const float* __restrict__ Xp,    // [B*S+1][8] packed records
    const f32x4* __restrict__ G4,    // [128][128]
    const float* __restrict__ Go,    // [128][256]
    const f32x4* __restrict__ Wg4,   // [7][128]
    const f32x2* __restrict__ Wgo2,  // [7][128]
    float* __restrict__ AB,          // [CHUNKS][B][2][256]
    float* __restrict__ Olast)       // [B][256]
{
    const int b = blockIdx.x;
    const int c = blockIdx.y;
    const int tid = threadIdx.x;     // 0..127, channels 2*tid, 2*tid+1

    const f32x4* __restrict__ xp =
        (const f32x4*)(Xp + ((size_t)b * NS + (size_t)c * STEPS) * 8);  // uniform
    const char* __restrict__ g4b = (const char*)G4;
    const int j16 = tid * 16;

    f32x4 w4[7];
    #pragma unroll
    for (int n = 0; n < 7; ++n) w4[n] = Wg4[n * 128 + tid];

    // prologue: step-0 record + table row
    f32x4 xa = xp[0], xb = xp[1];
    f32x4 g = *(const f32x4*)(g4b + __float_as_int(xa.x) + j16);

    float A0 = 1.f, B0 = 0.f, A1 = 1.f, B1 = 0.f;
    #pragma unroll 4
    for (int t = 0; t < STEPS; ++t) {
        // prefetch step t+1 (pad record at the very end keeps this branch-free)
        const f32x4 xa_n = xp[2 * t + 2];
        const f32x4 xb_n = xp[2 * t + 3];
        const f32x4 g_n = *(const f32x4*)(g4b + __float_as_int(xa_n.x) + j16);

        f32x4 acc = g;   // {z0', f0', z1', f1'} exp2-domain
        acc = __builtin_elementwise_fma(w4[0], splat4(xa.y), acc);
        acc = __builtin_elementwise_fma(w4[1], splat4(xa.z), acc);
        acc = __builtin_elementwise_fma(w4[2], splat4(xa.w), acc);
        acc = __builtin_elementwise_fma(w4[3], splat4(xb.x), acc);
        acc = __builtin_elementwise_fma(w4[4], splat4(xb.y), acc);
        acc = __builtin_elementwise_fma(w4[5], splat4(xb.z), acc);
        acc = __builtin_elementwise_fma(w4[6], splat4(xb.w), acc);

        const float ez0 = __builtin_amdgcn_exp2f(acc.x);   // exp(-2 gz0)
        const float ef0 = __builtin_amdgcn_exp2f(acc.y);   // exp(-gf0)
        const float ez1 = __builtin_amdgcn_exp2f(acc.z);
        const float ef1 = __builtin_amdgcn_exp2f(acc.w);
        const float az0 = 1.f + ez0, af0 = 1.f + ef0;
        const float az1 = 1.f + ez1, af1 = 1.f + ef1;
        const float r0 = __builtin_amdgcn_rcpf(az0 * af0);  // shared rcp
        const float r1 = __builtin_amdgcn_rcpf(az1 * af1);
        const float f0 = r0 * az0;                          // sigmoid(gf0)
        const float f1 = r1 * az1;
        const float z0 = fmaf(2.f, r0 * af0, -1.f);         // tanh(gz0)
        const float z1 = fmaf(2.f, r1 * af1, -1.f);

        A0 *= f0; B0 = fmaf(f0, B0 - z0, z0);
        A1 *= f1; B1 = fmaf(f1, B1 - z1, z1);

        g = g_n; xa = xa_n; xb = xb_n;
    }

    *(f32x2*)(AB + (((size_t)c * NB + b) * 2 + 0) * NH + 2 * tid) = (f32x2){A0, A1};
    *(f32x2*)(AB + (((size_t)c * NB + b) * 2 + 1) * NH + 2 * tid) = (f32x2){B0, B1};

    if (c == CHUNKS - 1) {
        const f32x4 la = xp[2 * (STEPS - 1)];
        const f32x4 lb = xp[2 * (STEPS - 1) + 1];
        const int eol = __float_as_int(la.x);
        f32x2 go = *(const f32x2*)((const char*)Go + (eol >> 1) + tid * 8);
        const float xs[7] = {la.y, la.z, la.w, lb.x, lb.y, lb.z, lb.w};
        #pragma unroll
        for (int n = 0; n < 7; ++n) {
            const f32x2 wg = Wgo2[n * 128 + tid];
            go.x = fmaf(wg.x, xs[n], go.x);
            go.y = fmaf(wg.y, xs[n], go.y);
        }
        const float o0 = __builtin_amdgcn_rcpf(1.f + __builtin_amdgcn_exp2f(go.x));
        const float o1 = __builtin_amdgcn_rcpf(1.f + __builtin_amdgcn_exp2f(go.y));
        *(f32x2*)(Olast + b * NH + 2 * tid) = (f32x2){o0, o1};
    }
}

__global__ __launch_bounds__(256) void combine_kernel(
    const float* __restrict__ AB,     // [CHUNKS][B][2][256]
    const float* __restrict__ Olast,  // [B][256]
    const float* __restrict__ Wout,   // [1][256]
    const float* __restrict__ bout,   // [1]
    float* __restrict__ out)          // [B][1]
{
    const int b = blockIdx.x;
    const int j = threadIdx.x;

    float h = 0.0f;
    #pragma unroll 8
    for (int c = 0; c < CHUNKS; ++c) {
        const float A  = AB[(((size_t)c * NB + b) * 2 + 0) * NH + j];
        const float Bv = AB[(((size_t)c * NB + b) * 2 + 1) * NH + j];
        h = fmaf(A, h, Bv);
    }
    float v = Olast[b * NH + j] * h * Wout[j];

    #pragma unroll
    for (int off = 32; off > 0; off >>= 1) v += __shfl_down(v, off);
    __shared__ float red[4];
    if ((j & 63) == 0) red[j >> 6] = v;
    __syncthreads();
    if (j == 0) out[b] = red[0] + red[1] + red[2] + red[3] + bout[0];
}

extern "C" void kernel_launch(void* const* d_in, const int* in_sizes, int n_in,
                              void* d_out, int out_size, void* d_ws, size_t ws_size,
                              hipStream_t stream) {
    const float* X    = (const float*)d_in[0];
    const float* emb  = (const float*)d_in[1];
    const float* Wn   = (const float*)d_in[2];
    const float* bn   = (const float*)d_in[3];
    const float* Wc   = (const float*)d_in[4];
    const float* bc   = (const float*)d_in[5];
    const float* Wout = (const float*)d_in[6];
    const float* bout = (const float*)d_in[7];
    float* out = (float*)d_out;

    f32x4* G4   = (f32x4*)d_ws;                        // 128*128 f32x4 (256 KB)
    float* Go   = (float*)(G4 + 128 * 128);            // 128*256 (128 KB)
    f32x4* Wg4  = (f32x4*)(Go + 128 * NH);             // 7*128 f32x4
    f32x2* Wgo2 = (f32x2*)(Wg4 + 7 * 128);             // 7*128 f32x2
    float* AB   = (float*)(Wgo2 + 7 * 128);            // 32*64*2*256 (4 MB)
    float* Ol   = AB + (size_t)CHUNKS * NB * 2 * NH;   // 64*256
    float* Xp   = Ol + NB * NH;                        // (64*2048+1)*8 floats

    precompute_kernel<<<193, 256, 0, stream>>>(X, emb, Wn, bn, Wc, bc,
                                               G4, Go, Wg4, Wgo2, Xp);
    dim3 grid(NB, CHUNKS);
    scan_kernel<<<grid, 128, 0, stream>>>(Xp, G4, Go, Wg4, Wgo2, AB, Ol);
    combine_kernel<<<NB, 256, 0, stream>>>(AB, Ol, Wout, bout, out);
}